// Round 17
// baseline (654.911 us; speedup 1.0000x reference)
//
#include <hip/hip_runtime.h>
#include <float.h>

typedef unsigned short ushort_t;
typedef short bf16x8 __attribute__((ext_vector_type(8)));     // 8 bf16 (guide-verified operand type)
typedef _Float16 f16x8 __attribute__((ext_vector_type(8)));   // 8 f16
typedef float f32x4 __attribute__((ext_vector_type(4)));

#define NS 4096
#define ND 64
#define NU 45
#define NUP 48

__device__ __forceinline__ float bf2f(ushort_t u){ return __uint_as_float(((unsigned)u)<<16); }
__device__ __forceinline__ ushort_t f2bf(float f){
  unsigned u = __float_as_uint(f);
  u += 0x7fffu + ((u>>16)&1u);   // RNE
  return (ushort_t)(u>>16);
}
__device__ __forceinline__ ushort_t f2h(float f){ _Float16 h=(_Float16)f; return __builtin_bit_cast(ushort_t, h); }
__device__ __forceinline__ float h2f(ushort_t u){ return (float)__builtin_bit_cast(_Float16, u); }

// async global -> LDS, 16B per lane; LDS dest = wave-uniform base + lane*16
__device__ __forceinline__ void gload16(const ushort_t* g, ushort_t* l)
{
  __builtin_amdgcn_global_load_lds(
      (const __attribute__((address_space(1))) unsigned int*)(g),
      (__attribute__((address_space(3))) unsigned int*)(l),
      16, 0, 0);
}

// ---------------------------------------------------------------------------
// 1) PREP: blk<192 -> W split+transpose (+Wpsum); blk>=192 -> x hi/lo split
// ---------------------------------------------------------------------------
__global__ __launch_bounds__(256) void k_prep(const float* __restrict__ Wq,
                                              const float* __restrict__ Wk,
                                              const float* __restrict__ Wv,
                                              const float* __restrict__ Wp,
                                              const float* __restrict__ x,
                                              ushort_t* __restrict__ wh,
                                              ushort_t* __restrict__ wl,
                                              float* __restrict__ Wpsum,
                                              ushort_t* __restrict__ xh,
                                              ushort_t* __restrict__ xl)
{
  __shared__ float tile[64][65];
  const int blk = blockIdx.x;
  const int t = threadIdx.x;
  if (blk >= 192) {                      // xsplit: 16384 blocks, 4 elems/thread
    int i = ((blk - 192)*256 + t)*4;
    float4 v = *(const float4*)(x + i);
    ushort4 h, lo;
    h.x = f2bf(v.x); lo.x = f2bf(v.x - bf2f(h.x));
    h.y = f2bf(v.y); lo.y = f2bf(v.y - bf2f(h.y));
    h.z = f2bf(v.z); lo.z = f2bf(v.z - bf2f(h.z));
    h.w = f2bf(v.w); lo.w = f2bf(v.w - bf2f(h.w));
    *(ushort4*)(xh + i) = h;
    *(ushort4*)(xl + i) = lo;
    return;
  }
  // wsplit: 192 = 3 mats x 8 kt x 8 nt
  const int mat = blk >> 6;
  const int kt = (blk >> 3) & 7, nt = blk & 7;
  const float* W = (mat == 0) ? Wq : (mat == 1 ? Wk : Wv);
  const int rr = t >> 6, cc = t & 63;
  #pragma unroll
  for (int i = 0; i < 16; i++)
    tile[rr*16 + i][cc] = W[(size_t)(kt*64 + rr*16 + i)*512 + nt*64 + cc];
  __syncthreads();
  #pragma unroll
  for (int i = 0; i < 16; i++) {
    const int n = rr*16 + i;
    const float v = tile[cc][n];         // W[kt*64+cc][nt*64+n]
    const ushort_t h = f2bf(v);
    const size_t o = (size_t)(mat*512 + nt*64 + n)*512 + kt*64 + cc;
    wh[o] = h;
    wl[o] = f2bf(v - bf2f(h));
  }
  if (blk < 128) {                       // fused Wpsum: [d2][c] = sum_j Wp[j*64+d2][c]
    const int i = blk*256 + t;
    const int d2 = i >> 9, c = i & 511;
    float s = 0.f;
    #pragma unroll
    for (int j = 0; j < 8; j++) s += Wp[(size_t)(j*64 + d2)*512 + c];
    Wpsum[i] = s;
  }
}

// ---------------------------------------------------------------------------
// 2) Unified QKV projection, grid (12,256): uniform 3-term split-bf16 MFMA
//    for all col-tiles (q cols 0-511, k 512-1023, v 1024-1535).
//    Staging via global_load_lds (4 planes, wave-per-plane, NI=10).
//    Epilogues: q -> qb16 (1 LDS pass); k -> kb16+kl16 (2 passes);
//               v -> vfT f16 TRANSPOSED.
// ---------------------------------------------------------------------------
__global__ __launch_bounds__(256) void k_gemm(
    const ushort_t* __restrict__ xh, const ushort_t* __restrict__ xl,
    const ushort_t* __restrict__ wh, const ushort_t* __restrict__ wl,
    const float* __restrict__ bq, const float* __restrict__ bk, const float* __restrict__ bv,
    ushort_t* __restrict__ vfT, ushort_t* __restrict__ kb16,
    ushort_t* __restrict__ kl16, ushort_t* __restrict__ qb16)
{
  __shared__ __align__(16) ushort_t smem[20480];      // 40 KiB stage / 34.8 KiB epilogue transpose
  ushort_t* Ah = smem;
  ushort_t* Al = smem + 5120;
  ushort_t* Bh = smem + 10240;
  ushort_t* Bl = smem + 15360;
  const int p = blockIdx.y * 12 + blockIdx.x;
  const int cx = p & 7;               // XCD slot
  const int local = p >> 3;           // 0..383
  const int by = cx*32 + local/12;    // 32 row-panels per XCD chunk
  const int bx = local % 12;
  const int rowbase = by * 128;
  const int colbase = bx * 128;
  const int mat = colbase >> 9;       // 0=q 1=k 2=v
  const int t = threadIdx.x;
  const int l = t & 63;
  const int w = t >> 6;
  const int wm = w >> 1, wn = w & 1;
  f32x4 acc[4][4] = {};

  // staging precompute: wave w owns one plane
  const ushort_t* srcp = (w == 0) ? xh : (w == 1) ? xl : (w == 2) ? wh : wl;
  const int prow = (w < 2) ? rowbase : colbase;
  ushort_t* ldsw = smem + w*5120;
  int goff[10];
  #pragma unroll
  for (int i = 0; i < 10; i++) {
    const int off = i*1024 + l*16;           // byte offset in plane
    const int row = off / 80;
    int cus = (off - row*80) >> 1;           // ushort col: {0,8,16,24,32}
    if (cus >= 32) cus = 0;                  // pad chunk -> dummy load
    goff[i] = (prow + row)*512 + cus;
  }

  for (int k0 = 0; k0 < 512; k0 += 32) {
    __syncthreads();
    #pragma unroll
    for (int i = 0; i < 10; i++)
      gload16(srcp + goff[i] + k0, ldsw + i*512);
    __syncthreads();
    bf16x8 ah[4], al[4], bh8[4], bl8[4];
    #pragma unroll
    for (int m = 0; m < 4; m++) {
      const int off = (wm*64 + m*16 + (l & 15))*40 + (l >> 4)*8;
      ah[m] = *(const bf16x8*)(&Ah[off]);
      al[m] = *(const bf16x8*)(&Al[off]);
    }
    #pragma unroll
    for (int n = 0; n < 4; n++) {
      const int off = (wn*64 + n*16 + (l & 15))*40 + (l >> 4)*8;
      bh8[n] = *(const bf16x8*)(&Bh[off]);
      bl8[n] = *(const bf16x8*)(&Bl[off]);
    }
    #pragma unroll
    for (int m = 0; m < 4; m++)
      #pragma unroll
      for (int n = 0; n < 4; n++) {
        acc[m][n] = __builtin_amdgcn_mfma_f32_16x16x32_bf16(ah[m], bh8[n], acc[m][n], 0, 0, 0);
        acc[m][n] = __builtin_amdgcn_mfma_f32_16x16x32_bf16(ah[m], bl8[n], acc[m][n], 0, 0, 0);
        acc[m][n] = __builtin_amdgcn_mfma_f32_16x16x32_bf16(al[m], bh8[n], acc[m][n], 0, 0, 0);
      }
  }

  if (mat == 2) {
    // v: LDS transpose then coalesced 128B vfT row-segment writes
    __syncthreads();
    #pragma unroll
    for (int n = 0; n < 4; n++) {
      const int wi_l = wn*64 + n*16 + (l & 15);
      const float bias = bv[(colbase & 511) + wi_l];
      #pragma unroll
      for (int m = 0; m < 4; m++) {
        const int nr_l = wm*64 + m*16 + ((l >> 4) << 2);
        ushort4 pk;
        pk.x = f2h(acc[m][n][0] + bias);
        pk.y = f2h(acc[m][n][1] + bias);
        pk.z = f2h(acc[m][n][2] + bias);
        pk.w = f2h(acc[m][n][3] + bias);
        *(ushort4*)(&smem[wi_l*136 + nr_l]) = pk;   // [128 wi][136] f16, padded
      }
    }
    __syncthreads();
    const int wi2 = t >> 1, half = t & 1;
    const int cim = (colbase & 511) + wi2;
    const int hh2 = cim >> 6, d2 = cim & 63;
    const int b2 = rowbase >> 12;
    const int nr2 = (rowbase & 4095) + half*64;
    ushort_t* op = &vfT[((size_t)(b2*8 + hh2)*ND + d2)*NS + nr2];
    const ushort_t* ip = &smem[wi2*136 + half*64];
    #pragma unroll
    for (int cch = 0; cch < 8; cch++)
      *(uint4*)(op + cch*8) = *(const uint4*)(ip + cch*8);
    return;
  }

  // q / k: bf16 [bh][n][64] outputs via LDS transpose (k emits hi then lo)
  const float* bias_p = (mat == 0) ? bq : bk;
  const int npass = (mat == 0) ? 1 : 2;
  for (int pass = 0; pass < npass; pass++) {
    __syncthreads();
    #pragma unroll
    for (int n = 0; n < 4; n++) {
      const int c_l = wn*64 + n*16 + (l & 15);
      const float bias = bias_p[(colbase & 511) + c_l];
      #pragma unroll
      for (int m = 0; m < 4; m++) {
        const int rb_l = wm*64 + m*16 + ((l >> 4) << 2);
        #pragma unroll
        for (int j = 0; j < 4; j++) {
          const float val = acc[m][n][j] + bias;
          const ushort_t h = f2bf(val);
          smem[(rb_l + j)*136 + c_l] = (pass == 0) ? h : f2bf(val - bf2f(h));
        }
      }
    }
    __syncthreads();
    ushort_t* obuf = (mat == 0) ? qb16 : (pass == 0 ? kb16 : kl16);
    const int r2 = t >> 1, half = t & 1;
    const int hh2 = ((colbase & 511) >> 6) + half;
    const int b2 = rowbase >> 12;
    const int nr2 = rowbase & 4095;
    ushort_t* op = &obuf[((size_t)(b2*8 + hh2)*NS + nr2 + r2)*ND];
    const ushort_t* ip = &smem[r2*136 + half*64];
    #pragma unroll
    for (int cch = 0; cch < 8; cch++)
      *(uint4*)(op + cch*8) = *(const uint4*)(ip + cch*8);
  }
}

// ---------------------------------------------------------------------------
// 3) APPROX M from bf16 q,k: wave per query, 8 lanes per sample-row,
//    all 6 gathers force-hoisted into registers (deep MLP)
// ---------------------------------------------------------------------------
__global__ __launch_bounds__(256) void k_m_approx(const ushort_t* __restrict__ qb16,
                                                  const ushort_t* __restrict__ kb16,
                                                  const int* __restrict__ idxs,
                                                  float* __restrict__ Mv)
{
  __shared__ float qs[4][64];
  __shared__ int   sidx[4][48];
  const int orig = blockIdx.y * 1024 + blockIdx.x;
  const int lin  = (orig & 7) * 8192 + (orig >> 3);   // bijective XCD swizzle
  const int bh   = lin >> 10;
  const int lc   = lin & 1023;
  const int t = threadIdx.x;
  const int wv = t >> 6, lane = t & 63;
  const int l = lc*4 + wv;
  qs[wv][lane] = bf2f(qb16[((size_t)bh*NS + l)*ND + lane]);
  for (int e = t; e < 4*NU; e += 256)
    sidx[e/NU][e%NU] = idxs[(size_t)(lc*4 + e/NU)*NU + e%NU];
  __syncthreads();
  const int g  = lane >> 3;       // sample group 0..7
  const int dq = lane & 7;        // 8 bf16 at dq*8
  const float* qp = &qs[wv][dq*8];
  int ids[6];
  #pragma unroll
  for (int p = 0; p < 6; p++) {
    const int s = p*8 + g;
    ids[p] = sidx[wv][(s < NU) ? s : NU-1];
  }
  uint4 ku[6];
  #pragma unroll
  for (int p = 0; p < 6; p++)
    ku[p] = *(const uint4*)(&kb16[((size_t)bh*NS + ids[p])*ND + dq*8]);
  float mx = -FLT_MAX, sm = 0.f;
  #pragma unroll
  for (int p = 0; p < 6; p++) {
    const int s = p*8 + g;
    const bool val = (s < NU);
    const ushort_t* kp = (const ushort_t*)&ku[p];
    float p_dot = qp[0]*bf2f(kp[0]) + qp[1]*bf2f(kp[1]) + qp[2]*bf2f(kp[2]) + qp[3]*bf2f(kp[3])
                + qp[4]*bf2f(kp[4]) + qp[5]*bf2f(kp[5]) + qp[6]*bf2f(kp[6]) + qp[7]*bf2f(kp[7]);
    p_dot += __shfl_xor(p_dot, 1, 64);
    p_dot += __shfl_xor(p_dot, 2, 64);
    p_dot += __shfl_xor(p_dot, 4, 64);
    if (val) { mx = fmaxf(mx, p_dot); sm += p_dot; }
  }
  #pragma unroll
  for (int o = 8; o < 64; o <<= 1) {
    mx = fmaxf(mx, __shfl_xor(mx, o, 64));
    sm += __shfl_xor(sm, o, 64);
  }
  if (lane == 0) Mv[bh*NS + l] = mx - sm * (1.0f/(float)NS);
}

// ---------------------------------------------------------------------------
// 4) top-64 per (b,h): register-cached iterative argmax
// ---------------------------------------------------------------------------
template<int NSEL, int OST>
__global__ __launch_bounds__(256) void k_topk(const float* __restrict__ Mv, int* __restrict__ dst)
{
  __shared__ float wvs[4];
  __shared__ int   wis[4];
  const int bh = blockIdx.x, t = threadIdx.x;
  const int wv = t >> 6, lane = t & 63;
  float v[16];
  #pragma unroll
  for (int j = 0; j < 16; j++) v[j] = Mv[bh*NS + j*256 + t];
  unsigned removed = 0;
  float tmax = -FLT_MAX; int tidx = 0x7fffffff;
  #pragma unroll
  for (int j = 0; j < 16; j++) {
    if (v[j] > tmax) { tmax = v[j]; tidx = j*256 + t; }
  }
  for (int it = 0; it < NSEL; it++) {
    float mv = tmax; int mi = tidx;
    #pragma unroll
    for (int o = 1; o < 64; o <<= 1) {
      float vo = __shfl_xor(mv, o, 64); int io = __shfl_xor(mi, o, 64);
      if (vo > mv || (vo == mv && io < mi)) { mv = vo; mi = io; }
    }
    if (lane == 0) { wvs[wv] = mv; wis[wv] = mi; }
    __syncthreads();
    float gv = wvs[0]; int gi = wis[0];
    #pragma unroll
    for (int k2 = 1; k2 < 4; k2++) {
      float vo = wvs[k2]; int io = wis[k2];
      if (vo > gv || (vo == gv && io < gi)) { gv = vo; gi = io; }
    }
    if (t == 0) dst[bh*OST + it] = gi;
    if ((gi & 255) == t) {       // owner invalidates and rescans its 16
      removed |= 1u << (gi >> 8);
      tmax = -FLT_MAX; tidx = 0x7fffffff;
      #pragma unroll
      for (int j = 0; j < 16; j++) {
        bool ok = ((removed >> j) & 1u) == 0u;
        if (ok && (v[j] > tmax || (v[j] == tmax && (j*256+t) < tidx))) { tmax = v[j]; tidx = j*256 + t; }
      }
    }
    __syncthreads();
  }
}

// ---------------------------------------------------------------------------
// 4b) exact q for the 64 candidates: grid (4,64), wave w owns dim-tile w
// ---------------------------------------------------------------------------
__global__ __launch_bounds__(256) void k_qexact(const float* __restrict__ x,
                                                const ushort_t* __restrict__ wh,
                                                const ushort_t* __restrict__ wl,
                                                const float* __restrict__ bq,
                                                const int* __restrict__ Cand,
                                                float* __restrict__ qex)
{
  const int bh = blockIdx.y, qtr = blockIdx.x, t = threadIdx.x;
  const int w = t >> 6, l = t & 63;
  const int b = bh >> 3, h = bh & 7;
  const int cand = qtr*16 + (l & 15);
  const int n = Cand[bh*64 + cand];
  const float* xr = x + ((size_t)b*NS + n)*512 + (l >> 4)*8;
  f32x4 acc = {};
  for (int k0 = 0; k0 < 512; k0 += 32) {
    float4 v0 = *(const float4*)(xr + k0);
    float4 v1 = *(const float4*)(xr + k0 + 4);
    ushort_t hi[8], lo[8];
    float vv[8] = {v0.x,v0.y,v0.z,v0.w,v1.x,v1.y,v1.z,v1.w};
    #pragma unroll
    for (int j = 0; j < 8; j++) {
      hi[j] = f2bf(vv[j]);
      lo[j] = f2bf(vv[j] - bf2f(hi[j]));
    }
    bf16x8 ah = *(const bf16x8*)hi;
    bf16x8 al = *(const bf16x8*)lo;
    const size_t boff = (size_t)(h*64 + w*16 + (l & 15))*512 + k0 + (l >> 4)*8;
    bf16x8 bh8 = *(const bf16x8*)(&wh[boff]);
    bf16x8 bl8 = *(const bf16x8*)(&wl[boff]);
    acc = __builtin_amdgcn_mfma_f32_16x16x32_bf16(ah, bh8, acc, 0, 0, 0);
    acc = __builtin_amdgcn_mfma_f32_16x16x32_bf16(ah, bl8, acc, 0, 0, 0);
    acc = __builtin_amdgcn_mfma_f32_16x16x32_bf16(al, bh8, acc, 0, 0, 0);
  }
  #pragma unroll
  for (int j = 0; j < 4; j++) {
    const int cand_o = qtr*16 + (l >> 4)*4 + j;
    const int d_o = w*16 + (l & 15);
    qex[((size_t)bh*64 + cand_o)*ND + d_o] = acc[j] + bq[h*64 + d_o];
  }
}

// ---------------------------------------------------------------------------
// 4c) exact M for the 64 candidates: grid (4,64); k from kb16+kl16 pair
// ---------------------------------------------------------------------------
__global__ __launch_bounds__(256) void k_mexact(const float* __restrict__ qex,
                                                const ushort_t* __restrict__ kb16,
                                                const ushort_t* __restrict__ kl16,
                                                const int* __restrict__ idxs,
                                                const int* __restrict__ Cand,
                                                float* __restrict__ Mex)
{
  const int bh = blockIdx.y, qtr = blockIdx.x, t = threadIdx.x;
  const int c = qtr*16 + (t >> 4);
  const int dl = t & 15;                    // 4 elems at dl*4
  const int l = Cand[bh*64 + c];
  const float4 q4 = *(const float4*)(&qex[((size_t)bh*64 + c)*ND + dl*4]);
  const int* ib = idxs + (size_t)l*NU;
  float mx = -FLT_MAX, sm = 0.f;
  for (int s = 0; s < NU; s++) {
    const int id = ib[s];
    const size_t ko = ((size_t)bh*NS + id)*ND + dl*4;
    const ushort4 h4 = *(const ushort4*)(&kb16[ko]);
    const ushort4 l4 = *(const ushort4*)(&kl16[ko]);
    float p = q4.x*(bf2f(h4.x)+bf2f(l4.x)) + q4.y*(bf2f(h4.y)+bf2f(l4.y))
            + q4.z*(bf2f(h4.z)+bf2f(l4.z)) + q4.w*(bf2f(h4.w)+bf2f(l4.w));
    p += __shfl_xor(p, 1, 64);
    p += __shfl_xor(p, 2, 64);
    p += __shfl_xor(p, 4, 64);
    p += __shfl_xor(p, 8, 64);
    mx = fmaxf(mx, p);
    sm += p;
  }
  if (dl == 0) Mex[bh*64 + c] = mx - sm * (1.0f/(float)NS);
}

// ---------------------------------------------------------------------------
// 4d) fused top-45 + Qr gather (one block per bh)
// ---------------------------------------------------------------------------
__global__ __launch_bounds__(256) void k_selq(const float* __restrict__ Mex,
                                              const int* __restrict__ Cand,
                                              const float* __restrict__ qex,
                                              int* __restrict__ Mtop,
                                              ushort_t* __restrict__ Qr)
{
  __shared__ int MslotL[NU];
  const int bh = blockIdx.x, t = threadIdx.x;
  // phase 1: top-45 of 64 (wave 0; value desc, index asc)
  if (t < 64) {
    float val = Mex[bh*64 + t];
    const int n = Cand[bh*64 + t];
    const int slot = t;
    for (int it = 0; it < NU; it++) {
      float wv = val; int wn = n; int ws = slot;
      #pragma unroll
      for (int o = 1; o < 64; o <<= 1) {
        float vo = __shfl_xor(wv, o, 64); int io = __shfl_xor(wn, o, 64); int so = __shfl_xor(ws, o, 64);
        if (vo > wv || (vo == wv && io < wn)) { wv = vo; wn = io; ws = so; }
      }
      if (t == 0) { Mtop[bh*NUP + it] = wn; MslotL[it] = ws; }
      if (n == wn) val = -FLT_MAX;
    }
  }
  __syncthreads();
  // phase 2: Qr gather, pre-scaled by 0.125 (rows 45..47 zero)
  for (int e = t; e < NUP*ND; e += 256) {
    const int u = e >> 6, d = e & 63;
    float v = 0.f;
    if (u < NU) { const int s = MslotL[u]; v = qex[((size_t)bh*64 + s)*ND + d]; }
    Qr[bh*NUP*ND + e] = f2bf(v * 0.125f);
  }
}

// ---------------------------------------------------------------------------
// 6) FLASH: fused scores->softmax->PV with online softmax.
//    Grid 512 = 64 bh x 8 col-segments (blk&63=bh keeps bh on one XCD).
// ---------------------------------------------------------------------------
__global__ __launch_bounds__(256) void k_flash(const ushort_t* __restrict__ Qr,
                                               const ushort_t* __restrict__ kb16,
                                               const ushort_t* __restrict__ vfT,
                                               float* __restrict__ Opart,
                                               float* __restrict__ mpart,
                                               float* __restrict__ lpart)
{
  __shared__ __align__(16) ushort_t Plds[3][16][68];   // f16, wave-private
  const int blk = blockIdx.x;
  const int bh = blk & 63, seg = blk >> 6;
  const int t = threadIdx.x, w = t >> 6, l = t & 63;
  if (w >= 3) return;                                  // no barriers below
  const int row0 = w*16;
  bf16x8 aq[2];
  #pragma unroll
  for (int ks = 0; ks < 2; ks++)
    aq[ks] = *(const bf16x8*)(&Qr[((size_t)bh*NUP + row0 + (l & 15))*ND + ks*32 + (l >> 4)*8]);
  f32x4 o[4] = {};
  float m[4], ls[4];
  #pragma unroll
  for (int j = 0; j < 4; j++) { m[j] = -FLT_MAX; ls[j] = 0.f; }
  const int nbeg = seg*512;
  for (int nc = nbeg; nc < nbeg + 512; nc += 64) {
    f32x4 S[4];
    #pragma unroll
    for (int ct = 0; ct < 4; ct++) {
      f32x4 z = {};
      #pragma unroll
      for (int ks = 0; ks < 2; ks++) {
        bf16x8 bk8 = *(const bf16x8*)(&kb16[((size_t)bh*NS + nc + ct*16 + (l & 15))*ND + ks*32 + (l >> 4)*8]);
        z = __builtin_amdgcn_mfma_f32_16x16x32_bf16(aq[ks], bk8, z, 0, 0, 0);
      }
      S[ct] = z;
    }
    float mx[4];
    #pragma unroll
    for (int j = 0; j < 4; j++)
      mx[j] = fmaxf(fmaxf(S[0][j], S[1][j]), fmaxf(S[2][j], S[3][j]));
    #pragma unroll
    for (int o2 = 1; o2 < 16; o2 <<= 1)
      #pragma unroll
      for (int j = 0; j < 4; j++)
        mx[j] = fmaxf(mx[j], __shfl_xor(mx[j], o2, 64));
    float c[4];
    #pragma unroll
    for (int j = 0; j < 4; j++) {
      const float mn = fmaxf(m[j], mx[j]);
      c[j] = __expf(m[j] - mn);
      m[j] = mn;
      ls[j] *= c[j];
    }
    #pragma unroll
    for (int dt = 0; dt < 4; dt++)
      #pragma unroll
      for (int j = 0; j < 4; j++)
        o[dt][j] *= c[j];
    #pragma unroll
    for (int ct = 0; ct < 4; ct++)
      #pragma unroll
      for (int j = 0; j < 4; j++) {
        const float pv = __expf(S[ct][j] - m[j]);
        ls[j] += pv;
        Plds[w][(l >> 4)*4 + j][ct*16 + (l & 15)] = f2h(pv);
      }
    #pragma unroll
    for (int ks2 = 0; ks2 < 2; ks2++) {
      f16x8 ap = __builtin_bit_cast(f16x8, *(const uint4*)(&Plds[w][l & 15][ks2*32 + (l >> 4)*8]));
      #pragma unroll
      for (int dt = 0; dt < 4; dt++) {
        f16x8 bv8 = __builtin_bit_cast(f16x8, *(const uint4*)(&vfT[((size_t)bh*ND + dt*16 + (l & 15))*NS + nc + ks2*32 + (l >> 4)*8]));
        o[dt] = __builtin_amdgcn_mfma_f32_16x16x32_f16(ap, bv8, o[dt], 0, 0, 0);
      }
    }
  }
  #pragma unroll
  for (int o2 = 1; o2 < 16; o2 <<= 1)
    #pragma unroll
    for (int j = 0; j < 4; j++)
      ls[j] += __shfl_xor(ls[j], o2, 64);
  #pragma unroll
  for (int dt = 0; dt < 4; dt++)
    #pragma unroll
    for (int j = 0; j < 4; j++)
      Opart[(((size_t)bh*8 + seg)*NUP + row0 + (l >> 4)*4 + j)*ND + dt*16 + (l & 15)] = o[dt][j];
  if ((l & 15) == 0) {
    #pragma unroll
    for (int j = 0; j < 4; j++) {
      mpart[((size_t)bh*8 + seg)*NUP + row0 + (l >> 4)*4 + j] = m[j];
      lpart[((size_t)bh*8 + seg)*NUP + row0 + (l >> 4)*4 + j] = ls[j];
    }
  }
}

// ---------------------------------------------------------------------------
// 6b) combine 8 segment partials -> delta; fused uidx init (grid 1024)
// ---------------------------------------------------------------------------
__global__ __launch_bounds__(256) void k_combine(const float* __restrict__ Opart,
                                                 const float* __restrict__ mpart,
                                                 const float* __restrict__ lpart,
                                                 const float* __restrict__ vmean,
                                                 float* __restrict__ delta,
                                                 int* __restrict__ uidx)
{
  const int blk = blockIdx.x, t = threadIdx.x;
  uidx[blk*256 + t] = -1;
  if (blk >= 64) return;
  const int bh = blk;
  for (int e = t; e < NUP*ND; e += 256) {
    const int u = e >> 6, d = e & 63;
    float mg = -FLT_MAX;
    #pragma unroll
    for (int s = 0; s < 8; s++) mg = fmaxf(mg, mpart[((size_t)bh*8 + s)*NUP + u]);
    float On = 0.f, Ln = 0.f;
    #pragma unroll
    for (int s = 0; s < 8; s++) {
      const float wgt = __expf(mpart[((size_t)bh*8 + s)*NUP + u] - mg);
      On += wgt * Opart[(((size_t)bh*8 + s)*NUP + u)*ND + d];
      Ln += wgt * lpart[((size_t)bh*8 + s)*NUP + u];
    }
    delta[((size_t)bh*NUP + u)*ND + d] = On/Ln - vmean[bh*ND + d];
  }
}

// ---------------------------------------------------------------------------
// 8) v mean from vfT (one block per (bh,d), deterministic)
// ---------------------------------------------------------------------------
__global__ __launch_bounds__(256) void k_vmean(const ushort_t* __restrict__ vfT, float* __restrict__ vmean)
{
  __shared__ float red[256];
  const int d = blockIdx.x, bh = blockIdx.y, t = threadIdx.x;
  const ushort_t* vr = vfT + ((size_t)bh*ND + d)*NS;
  float s = 0.f;
  for (int n = t; n < NS; n += 256) s += h2f(vr[n]);
  red[t] = s; __syncthreads();
  for (int st = 128; st > 0; st >>= 1) { if (t < st) red[t] += red[t+st]; __syncthreads(); }
  if (t == 0) vmean[bh*ND + d] = red[0] * (1.0f/(float)NS);
}

// ---------------------------------------------------------------------------
// 10) scatter row-id map (uidx pre-initialized by k_combine)
// ---------------------------------------------------------------------------
__global__ void k_scatter(const int* __restrict__ Mtop, int* __restrict__ uidx)
{
  const int bh = blockIdx.x, t = threadIdx.x;  // 64 threads
  if (t < NU) {
    const int n = Mtop[bh*NUP + t];
    const int b = bh >> 3, h = bh & 7;
    const int nprime = h*512 + (n >> 3);       // reference's reshape-without-transpose
    uidx[((size_t)b*NS + nprime)*8 + (n & 7)] = bh*NUP + t;
  }
}

// ---------------------------------------------------------------------------
// 11) corr (u<45) + base (u==45), grid (46, 64)
// ---------------------------------------------------------------------------
__global__ __launch_bounds__(256) void k_corrbase(const float* __restrict__ delta,
                                                  const float* __restrict__ Wp,
                                                  const int* __restrict__ Mtop,
                                                  const float* __restrict__ vmean,
                                                  const float* __restrict__ Wpsum,
                                                  const float* __restrict__ bp,
                                                  float* __restrict__ corr,
                                                  float* __restrict__ basep)
{
  __shared__ float dl[64];
  const int bh = blockIdx.y, u = blockIdx.x, t = threadIdx.x;
  if (u == 45) {
    if (t < 64) dl[t] = vmean[bh*ND + t];
    __syncthreads();
    for (int c = t; c < 512; c += 256) {
      float s = bp[c];
      #pragma unroll 8
      for (int d2 = 0; d2 < 64; d2++) s += dl[d2] * Wpsum[d2*512 + c];
      basep[bh*512 + c] = s;
    }
    return;
  }
  const int n = Mtop[bh*NUP + u];
  const int j = n & 7;
  if (t < 64) dl[t] = delta[((size_t)bh*NUP + u)*ND + t];
  __syncthreads();
  for (int c = t; c < 512; c += 256) {
    float s = 0.f;
    #pragma unroll 8
    for (int d2 = 0; d2 < 64; d2++) s += dl[d2] * Wp[(size_t)(j*64 + d2)*512 + c];
    corr[((size_t)bh*NUP + u)*512 + c] = s;
  }
}

// ---------------------------------------------------------------------------
// 13) assemble output rows (f32)
// ---------------------------------------------------------------------------
__global__ __launch_bounds__(256) void k_assemble(const float* __restrict__ basep,
                                                  const float* __restrict__ corr,
                                                  const int* __restrict__ uidx,
                                                  float* __restrict__ out)
{
  const int b = blockIdx.y, nprime = blockIdx.x, t = threadIdx.x;
  const int h = nprime >> 9;
  const int* ui = uidx + ((size_t)b*NS + nprime)*8;
  float v0 = basep[(b*8 + h)*512 + t];
  float v1 = basep[(b*8 + h)*512 + 256 + t];
  #pragma unroll
  for (int j = 0; j < 8; j++) {
    const int id = ui[j];
    if (id >= 0) { v0 += corr[(size_t)id*512 + t]; v1 += corr[(size_t)id*512 + 256 + t]; }
  }
  const size_t o = ((size_t)b*NS + nprime)*512;
  out[o + t]       = v0;
  out[o + 256 + t] = v1;
}

// ---------------------------------------------------------------------------
extern "C" void kernel_launch(void* const* d_in, const int* in_sizes, int n_in,
                              void* d_out, int out_size, void* d_ws, size_t ws_size,
                              hipStream_t stream)
{
  (void)in_sizes; (void)n_in; (void)out_size; (void)ws_size;
  const float* x  = (const float*)d_in[0];
  const float* Wq = (const float*)d_in[1];
  const float* bq = (const float*)d_in[2];
  const float* Wk = (const float*)d_in[3];
  const float* bk = (const float*)d_in[4];
  const float* Wv = (const float*)d_in[5];
  const float* bv = (const float*)d_in[6];
  const float* Wp = (const float*)d_in[7];
  const float* bp = (const float*)d_in[8];
  const int* idxs = (const int*)d_in[9];
  float* out      = (float*)d_out;

  // workspace carve-up (peak 205.7 MB; ws >= 205,975,552 established)
  char* w = (char*)d_ws;
  ushort_t* vfT   = (ushort_t*)(w);                 // 33,554,432  [64][64][4096] f16
  ushort_t* kb16  = (ushort_t*)(w + 33554432);      // 33,554,432  [64][4096][64] bf16 (hi)
  ushort_t* kl16  = (ushort_t*)(w + 67108864);      // 33,554,432  (lo)
  ushort_t* qb16  = (ushort_t*)(w + 100663296);     // 33,554,432
  ushort_t* xh    = (ushort_t*)(w + 134217728);     // 33,554,432  (dead after k_gemm -> tail aliases)
  ushort_t* xl    = (ushort_t*)(w + 167772160);     // 33,554,432  (dead after k_gemm)
  ushort_t* wh    = (ushort_t*)(w + 201326592);     //  1,572,864
  ushort_t* wl    = (ushort_t*)(w + 202899456);     //  1,572,864
  float*    Mv    = (float*)(w + 204472320);        //  1,048,576  (dead after k_topk)
  float*    qex   = (float*)(w + 204472320);        // ALIAS of Mv: [64][64][64] f32
  int*      Mtop  = (int*)(w + 205520896);          //     12,288
  int*      Cand  = (int*)(w + 205533184);          //     16,384
  float*    vmean = (float*)(w + 205549568);        //     16,384
  float*    Wpsum = (float*)(w + 205565952);        //    131,072
  float*    Mex   = (float*)(w + 205697024);        //     16,384  -> end 205,713,408
  // tail aliases over the dead xh region (valid after k_gemm):
  float*    delta  = (float*)(w + 134217728);       //    786,432
  float*    corr   = (float*)(w + 135004160);       //  6,291,456
  int*      uidx   = (int*)(w + 141295616);         //  1,048,576
  float*    basep  = (float*)(w + 142344192);       //    131,072
  float*    Opart  = (float*)(w + 142475264);       //  6,291,456  [64][8][48][64]
  float*    mpart  = (float*)(w + 148766720);       //     98,304
  float*    lpart  = (float*)(w + 148865024);       //     98,304
  ushort_t* Qr     = (ushort_t*)(w + 148963328);    //    393,216  -> 149,356,544

  k_prep     <<<16576, 256, 0, stream>>>(Wq, Wk, Wv, Wp, x, wh, wl, Wpsum, xh, xl);
  k_gemm     <<<dim3(12, 256), 256, 0, stream>>>(xh, xl, wh, wl, bq, bk, bv, vfT, kb16, kl16, qb16);
  k_m_approx <<<dim3(1024, 64), 256, 0, stream>>>(qb16, kb16, idxs, Mv);
  k_vmean    <<<dim3(64, 64), 256, 0, stream>>>(vfT, vmean);
  k_topk<64,64> <<<64, 256, 0, stream>>>(Mv, Cand);
  // Mv dead; qex (same region) written next
  k_qexact   <<<dim3(4, 64), 256, 0, stream>>>(x, wh, wl, bq, Cand, qex);
  k_mexact   <<<dim3(4, 64), 256, 0, stream>>>(qex, kb16, kl16, idxs, Cand, Mex);
  k_selq     <<<64, 256, 0, stream>>>(Mex, Cand, qex, Mtop, Qr);
  k_flash    <<<512, 256, 0, stream>>>(Qr, kb16, vfT, Opart, mpart, lpart);
  k_combine  <<<1024, 256, 0, stream>>>(Opart, mpart, lpart, vmean, delta, uidx);
  k_scatter  <<<64, 64, 0, stream>>>(Mtop, uidx);
  k_corrbase <<<dim3(46, 64), 256, 0, stream>>>(delta, Wp, Mtop, vmean, Wpsum, bp, corr, basep);
  k_assemble <<<dim3(4096, 8), 256, 0, stream>>>(basep, corr, uidx, out);
}

// Round 18
// 520.337 us; speedup vs baseline: 1.2586x; 1.2586x over previous
//
#include <hip/hip_runtime.h>
#include <float.h>

typedef unsigned short ushort_t;
typedef short bf16x8 __attribute__((ext_vector_type(8)));     // 8 bf16 (guide-verified operand type)
typedef _Float16 f16x8 __attribute__((ext_vector_type(8)));   // 8 f16
typedef float f32x4 __attribute__((ext_vector_type(4)));

#define NS 4096
#define ND 64
#define NU 45
#define NUP 48

__device__ __forceinline__ float bf2f(ushort_t u){ return __uint_as_float(((unsigned)u)<<16); }
__device__ __forceinline__ ushort_t f2bf(float f){
  unsigned u = __float_as_uint(f);
  u += 0x7fffu + ((u>>16)&1u);   // RNE
  return (ushort_t)(u>>16);
}
__device__ __forceinline__ ushort_t f2h(float f){ _Float16 h=(_Float16)f; return __builtin_bit_cast(ushort_t, h); }
__device__ __forceinline__ float h2f(ushort_t u){ return (float)__builtin_bit_cast(_Float16, u); }

// async global -> LDS, 16B per lane; LDS dest = wave-uniform base + lane*16
__device__ __forceinline__ void gload16(const ushort_t* g, ushort_t* l)
{
  __builtin_amdgcn_global_load_lds(
      (const __attribute__((address_space(1))) unsigned int*)(g),
      (__attribute__((address_space(3))) unsigned int*)(l),
      16, 0, 0);
}

// ---------------------------------------------------------------------------
// 1) PREP: blk<192 -> W split+transpose (+Wpsum); blk>=192 -> x hi/lo split
// ---------------------------------------------------------------------------
__global__ __launch_bounds__(256) void k_prep(const float* __restrict__ Wq,
                                              const float* __restrict__ Wk,
                                              const float* __restrict__ Wv,
                                              const float* __restrict__ Wp,
                                              const float* __restrict__ x,
                                              ushort_t* __restrict__ wh,
                                              ushort_t* __restrict__ wl,
                                              float* __restrict__ Wpsum,
                                              ushort_t* __restrict__ xh,
                                              ushort_t* __restrict__ xl)
{
  __shared__ float tile[64][65];
  const int blk = blockIdx.x;
  const int t = threadIdx.x;
  if (blk >= 192) {                      // xsplit: 16384 blocks, 4 elems/thread
    int i = ((blk - 192)*256 + t)*4;
    float4 v = *(const float4*)(x + i);
    ushort4 h, lo;
    h.x = f2bf(v.x); lo.x = f2bf(v.x - bf2f(h.x));
    h.y = f2bf(v.y); lo.y = f2bf(v.y - bf2f(h.y));
    h.z = f2bf(v.z); lo.z = f2bf(v.z - bf2f(h.z));
    h.w = f2bf(v.w); lo.w = f2bf(v.w - bf2f(h.w));
    *(ushort4*)(xh + i) = h;
    *(ushort4*)(xl + i) = lo;
    return;
  }
  // wsplit: 192 = 3 mats x 8 kt x 8 nt
  const int mat = blk >> 6;
  const int kt = (blk >> 3) & 7, nt = blk & 7;
  const float* W = (mat == 0) ? Wq : (mat == 1 ? Wk : Wv);
  const int rr = t >> 6, cc = t & 63;
  #pragma unroll
  for (int i = 0; i < 16; i++)
    tile[rr*16 + i][cc] = W[(size_t)(kt*64 + rr*16 + i)*512 + nt*64 + cc];
  __syncthreads();
  #pragma unroll
  for (int i = 0; i < 16; i++) {
    const int n = rr*16 + i;
    const float v = tile[cc][n];         // W[kt*64+cc][nt*64+n]
    const ushort_t h = f2bf(v);
    const size_t o = (size_t)(mat*512 + nt*64 + n)*512 + kt*64 + cc;
    wh[o] = h;
    wl[o] = f2bf(v - bf2f(h));
  }
  if (blk < 128) {                       // fused Wpsum: [d2][c] = sum_j Wp[j*64+d2][c]
    const int i = blk*256 + t;
    const int d2 = i >> 9, c = i & 511;
    float s = 0.f;
    #pragma unroll
    for (int j = 0; j < 8; j++) s += Wp[(size_t)(j*64 + d2)*512 + c];
    Wpsum[i] = s;
  }
}

// ---------------------------------------------------------------------------
// 2) QKV projection (round-16 proven structure, ~133 us, VGPR 104):
//    staging via global_load_lds; LDS planes [128 rows][40 ushort].
//    MODE 0: q, 1-term (planes Ah,Bh)  -> qb16 bf16 via LDS transpose
//    MODE 1: kv, 3-term (planes Ah,Al,Bh,Bl)
//            -> kf f32 direct + kb16 bf16 via LDS; v f16 TRANSPOSED via LDS
// ---------------------------------------------------------------------------
template<int MODE>
__global__ __launch_bounds__(256) void k_gemm(
    const ushort_t* __restrict__ xh, const ushort_t* __restrict__ xl,
    const ushort_t* __restrict__ wh, const ushort_t* __restrict__ wl,
    const float* __restrict__ bq, const float* __restrict__ bk, const float* __restrict__ bv,
    float* __restrict__ kf, ushort_t* __restrict__ vfT,
    ushort_t* __restrict__ kb16, ushort_t* __restrict__ qb16)
{
  __shared__ __align__(16) ushort_t smem[20480];      // 40 KiB stage / 34.8 KiB epilogue transpose
  ushort_t* Ah = smem;
  ushort_t* Al = smem + 5120;                          // MODE1 only
  ushort_t* Bh = smem + (MODE == 1 ? 10240 : 5120);
  ushort_t* Bl = smem + 15360;                         // MODE1 only
  const int nbx = (MODE == 0) ? 4 : 8;
  const int p = blockIdx.y * nbx + blockIdx.x;
  const int cx = p & 7;               // XCD slot
  const int local = p >> 3;
  const int by = cx*32 + local/nbx;   // 32 row-panels per XCD chunk
  const int bx = local % nbx;
  const int rowbase = by * 128;
  const int colbase = (MODE == 0 ? 0 : 512) + bx*128;
  const int mat = colbase >> 9;       // 0=q 1=k 2=v
  const int t = threadIdx.x;
  const int l = t & 63;
  const int w = t >> 6;
  const int wm = w >> 1, wn = w & 1;
  f32x4 acc[4][4] = {};

  // --- staging precompute: per-wave plane + per-lane global offsets -------
  const int NI = (MODE == 1) ? 10 : 5;       // 16B instrs per wave
  const ushort_t* srcp;
  int prow;
  ushort_t* ldsw;
  if (MODE == 1) {
    srcp = (w == 0) ? xh : (w == 1) ? xl : (w == 2) ? wh : wl;
    prow = (w < 2) ? rowbase : colbase;
    ldsw = smem + w*5120;
  } else {
    srcp = (w < 2) ? xh : wh;
    prow = (w < 2) ? rowbase : colbase;
    ldsw = smem + (w >> 1)*5120 + (w & 1)*2560;
  }
  int goff[10];
  #pragma unroll
  for (int i = 0; i < 10; i++) {
    if (i >= NI) break;
    const int off = ((MODE == 0) ? (w & 1)*5120 : 0) + i*1024 + l*16;  // byte off in plane
    const int row = off / 80;
    int cus = (off - row*80) >> 1;          // ushort col: {0,8,16,24,32}
    if (cus >= 32) cus = 0;                  // pad chunk -> dummy load
    goff[i] = (prow + row)*512 + cus;
  }

  for (int k0 = 0; k0 < 512; k0 += 32) {
    __syncthreads();
    #pragma unroll
    for (int i = 0; i < 10; i++) {
      if (i >= NI) break;
      gload16(srcp + goff[i] + k0, ldsw + i*512);
    }
    __syncthreads();
    bf16x8 ah[4], al[4], bh8[4], bl8[4];
    #pragma unroll
    for (int m = 0; m < 4; m++) {
      const int off = (wm*64 + m*16 + (l & 15))*40 + (l >> 4)*8;
      ah[m] = *(const bf16x8*)(&Ah[off]);
      if (MODE == 1) al[m] = *(const bf16x8*)(&Al[off]);
    }
    #pragma unroll
    for (int n = 0; n < 4; n++) {
      const int off = (wn*64 + n*16 + (l & 15))*40 + (l >> 4)*8;
      bh8[n] = *(const bf16x8*)(&Bh[off]);
      if (MODE == 1) bl8[n] = *(const bf16x8*)(&Bl[off]);
    }
    #pragma unroll
    for (int m = 0; m < 4; m++)
      #pragma unroll
      for (int n = 0; n < 4; n++) {
        acc[m][n] = __builtin_amdgcn_mfma_f32_16x16x32_bf16(ah[m], bh8[n], acc[m][n], 0, 0, 0);
        if (MODE == 1) {
          acc[m][n] = __builtin_amdgcn_mfma_f32_16x16x32_bf16(ah[m], bl8[n], acc[m][n], 0, 0, 0);
          acc[m][n] = __builtin_amdgcn_mfma_f32_16x16x32_bf16(al[m], bh8[n], acc[m][n], 0, 0, 0);
        }
      }
  }

  if (MODE == 1 && mat == 2) {
    // v: LDS transpose then coalesced 128B vfT row-segment writes
    __syncthreads();
    #pragma unroll
    for (int n = 0; n < 4; n++) {
      const int wi_l = wn*64 + n*16 + (l & 15);
      const float bias = bv[(colbase & 511) + wi_l];
      #pragma unroll
      for (int m = 0; m < 4; m++) {
        const int nr_l = wm*64 + m*16 + ((l >> 4) << 2);
        ushort4 pk;
        pk.x = f2h(acc[m][n][0] + bias);
        pk.y = f2h(acc[m][n][1] + bias);
        pk.z = f2h(acc[m][n][2] + bias);
        pk.w = f2h(acc[m][n][3] + bias);
        *(ushort4*)(&smem[wi_l*136 + nr_l]) = pk;   // [128 wi][136] f16, padded
      }
    }
    __syncthreads();
    const int wi2 = t >> 1, half = t & 1;
    const int cim = (colbase & 511) + wi2;
    const int hh2 = cim >> 6, d2 = cim & 63;
    const int b2 = rowbase >> 12;
    const int nr2 = (rowbase & 4095) + half*64;
    ushort_t* op = &vfT[((size_t)(b2*8 + hh2)*ND + d2)*NS + nr2];
    const ushort_t* ip = &smem[wi2*136 + half*64];
    #pragma unroll
    for (int cch = 0; cch < 8; cch++)
      *(uint4*)(op + cch*8) = *(const uint4*)(ip + cch*8);
    return;
  }

  if (MODE == 1) {
    // k: direct f32 writes (aligned 64B row segments)
    #pragma unroll
    for (int n = 0; n < 4; n++) {
      const int wi = (colbase & 511) + wn*64 + n*16 + (l & 15);
      const int hh = wi >> 6, d = wi & 63;
      const float bias = bk[wi];
      #pragma unroll
      for (int m = 0; m < 4; m++) {
        const int rb = rowbase + wm*64 + m*16 + ((l >> 4) << 2);
        const int b  = rb >> 12, nr = rb & 4095;
        #pragma unroll
        for (int j = 0; j < 4; j++)
          kf[((size_t)(b*8 + hh)*NS + nr + j)*ND + d] = acc[m][n][j] + bias;
      }
    }
  }
  // bf16 [bh][n][64] output via LDS: kb16 (MODE1 k) or qb16 (MODE0)
  {
    ushort_t* obuf = (MODE == 0) ? qb16 : kb16;
    const float* bias_p = (MODE == 0) ? bq : bk;
    __syncthreads();
    #pragma unroll
    for (int n = 0; n < 4; n++) {
      const int c_l = wn*64 + n*16 + (l & 15);
      const float bias = bias_p[(colbase & 511) + c_l];
      #pragma unroll
      for (int m = 0; m < 4; m++) {
        const int rb_l = wm*64 + m*16 + ((l >> 4) << 2);
        #pragma unroll
        for (int j = 0; j < 4; j++)
          smem[(rb_l + j)*136 + c_l] = f2bf(acc[m][n][j] + bias);
      }
    }
    __syncthreads();
    const int r2 = t >> 1, half = t & 1;
    const int hh2 = ((colbase & 511) >> 6) + half;
    const int b2 = rowbase >> 12;
    const int nr2 = rowbase & 4095;
    ushort_t* op = &obuf[((size_t)(b2*8 + hh2)*NS + nr2 + r2)*ND];
    const ushort_t* ip = &smem[r2*136 + half*64];
    #pragma unroll
    for (int cch = 0; cch < 8; cch++)
      *(uint4*)(op + cch*8) = *(const uint4*)(ip + cch*8);
  }
}

// ---------------------------------------------------------------------------
// 3) APPROX M from bf16 q,k: wave per query, 8 lanes per sample-row,
//    all 6 gathers force-hoisted into registers (deep MLP)
// ---------------------------------------------------------------------------
__global__ __launch_bounds__(256) void k_m_approx(const ushort_t* __restrict__ qb16,
                                                  const ushort_t* __restrict__ kb16,
                                                  const int* __restrict__ idxs,
                                                  float* __restrict__ Mv)
{
  __shared__ float qs[4][64];
  __shared__ int   sidx[4][48];
  const int orig = blockIdx.y * 1024 + blockIdx.x;
  const int lin  = (orig & 7) * 8192 + (orig >> 3);   // bijective XCD swizzle
  const int bh   = lin >> 10;
  const int lc   = lin & 1023;
  const int t = threadIdx.x;
  const int wv = t >> 6, lane = t & 63;
  const int l = lc*4 + wv;
  qs[wv][lane] = bf2f(qb16[((size_t)bh*NS + l)*ND + lane]);
  for (int e = t; e < 4*NU; e += 256)
    sidx[e/NU][e%NU] = idxs[(size_t)(lc*4 + e/NU)*NU + e%NU];
  __syncthreads();
  const int g  = lane >> 3;       // sample group 0..7
  const int dq = lane & 7;        // 8 bf16 at dq*8
  const float* qp = &qs[wv][dq*8];
  int ids[6];
  #pragma unroll
  for (int p = 0; p < 6; p++) {
    const int s = p*8 + g;
    ids[p] = sidx[wv][(s < NU) ? s : NU-1];
  }
  uint4 ku[6];
  #pragma unroll
  for (int p = 0; p < 6; p++)
    ku[p] = *(const uint4*)(&kb16[((size_t)bh*NS + ids[p])*ND + dq*8]);
  float mx = -FLT_MAX, sm = 0.f;
  #pragma unroll
  for (int p = 0; p < 6; p++) {
    const int s = p*8 + g;
    const bool val = (s < NU);
    const ushort_t* kp = (const ushort_t*)&ku[p];
    float p_dot = qp[0]*bf2f(kp[0]) + qp[1]*bf2f(kp[1]) + qp[2]*bf2f(kp[2]) + qp[3]*bf2f(kp[3])
                + qp[4]*bf2f(kp[4]) + qp[5]*bf2f(kp[5]) + qp[6]*bf2f(kp[6]) + qp[7]*bf2f(kp[7]);
    p_dot += __shfl_xor(p_dot, 1, 64);
    p_dot += __shfl_xor(p_dot, 2, 64);
    p_dot += __shfl_xor(p_dot, 4, 64);
    if (val) { mx = fmaxf(mx, p_dot); sm += p_dot; }
  }
  #pragma unroll
  for (int o = 8; o < 64; o <<= 1) {
    mx = fmaxf(mx, __shfl_xor(mx, o, 64));
    sm += __shfl_xor(sm, o, 64);
  }
  if (lane == 0) Mv[bh*NS + l] = mx - sm * (1.0f/(float)NS);
}

// ---------------------------------------------------------------------------
// 4) top-64 per (b,h): register-cached iterative argmax
// ---------------------------------------------------------------------------
template<int NSEL, int OST>
__global__ __launch_bounds__(256) void k_topk(const float* __restrict__ Mv, int* __restrict__ dst)
{
  __shared__ float wvs[4];
  __shared__ int   wis[4];
  const int bh = blockIdx.x, t = threadIdx.x;
  const int wv = t >> 6, lane = t & 63;
  float v[16];
  #pragma unroll
  for (int j = 0; j < 16; j++) v[j] = Mv[bh*NS + j*256 + t];
  unsigned removed = 0;
  float tmax = -FLT_MAX; int tidx = 0x7fffffff;
  #pragma unroll
  for (int j = 0; j < 16; j++) {
    if (v[j] > tmax) { tmax = v[j]; tidx = j*256 + t; }
  }
  for (int it = 0; it < NSEL; it++) {
    float mv = tmax; int mi = tidx;
    #pragma unroll
    for (int o = 1; o < 64; o <<= 1) {
      float vo = __shfl_xor(mv, o, 64); int io = __shfl_xor(mi, o, 64);
      if (vo > mv || (vo == mv && io < mi)) { mv = vo; mi = io; }
    }
    if (lane == 0) { wvs[wv] = mv; wis[wv] = mi; }
    __syncthreads();
    float gv = wvs[0]; int gi = wis[0];
    #pragma unroll
    for (int k2 = 1; k2 < 4; k2++) {
      float vo = wvs[k2]; int io = wis[k2];
      if (vo > gv || (vo == gv && io < gi)) { gv = vo; gi = io; }
    }
    if (t == 0) dst[bh*OST + it] = gi;
    if ((gi & 255) == t) {       // owner invalidates and rescans its 16
      removed |= 1u << (gi >> 8);
      tmax = -FLT_MAX; tidx = 0x7fffffff;
      #pragma unroll
      for (int j = 0; j < 16; j++) {
        bool ok = ((removed >> j) & 1u) == 0u;
        if (ok && (v[j] > tmax || (v[j] == tmax && (j*256+t) < tidx))) { tmax = v[j]; tidx = j*256 + t; }
      }
    }
    __syncthreads();
  }
}

// ---------------------------------------------------------------------------
// 4b) exact q for the 64 candidates: grid (4,64), wave w owns dim-tile w
// ---------------------------------------------------------------------------
__global__ __launch_bounds__(256) void k_qexact(const float* __restrict__ x,
                                                const ushort_t* __restrict__ wh,
                                                const ushort_t* __restrict__ wl,
                                                const float* __restrict__ bq,
                                                const int* __restrict__ Cand,
                                                float* __restrict__ qex)
{
  const int bh = blockIdx.y, qtr = blockIdx.x, t = threadIdx.x;
  const int w = t >> 6, l = t & 63;
  const int b = bh >> 3, h = bh & 7;
  const int cand = qtr*16 + (l & 15);
  const int n = Cand[bh*64 + cand];
  const float* xr = x + ((size_t)b*NS + n)*512 + (l >> 4)*8;
  f32x4 acc = {};
  for (int k0 = 0; k0 < 512; k0 += 32) {
    float4 v0 = *(const float4*)(xr + k0);
    float4 v1 = *(const float4*)(xr + k0 + 4);
    ushort_t hi[8], lo[8];
    float vv[8] = {v0.x,v0.y,v0.z,v0.w,v1.x,v1.y,v1.z,v1.w};
    #pragma unroll
    for (int j = 0; j < 8; j++) {
      hi[j] = f2bf(vv[j]);
      lo[j] = f2bf(vv[j] - bf2f(hi[j]));
    }
    bf16x8 ah = *(const bf16x8*)hi;
    bf16x8 al = *(const bf16x8*)lo;
    const size_t boff = (size_t)(h*64 + w*16 + (l & 15))*512 + k0 + (l >> 4)*8;
    bf16x8 bh8 = *(const bf16x8*)(&wh[boff]);
    bf16x8 bl8 = *(const bf16x8*)(&wl[boff]);
    acc = __builtin_amdgcn_mfma_f32_16x16x32_bf16(ah, bh8, acc, 0, 0, 0);
    acc = __builtin_amdgcn_mfma_f32_16x16x32_bf16(ah, bl8, acc, 0, 0, 0);
    acc = __builtin_amdgcn_mfma_f32_16x16x32_bf16(al, bh8, acc, 0, 0, 0);
  }
  #pragma unroll
  for (int j = 0; j < 4; j++) {
    const int cand_o = qtr*16 + (l >> 4)*4 + j;
    const int d_o = w*16 + (l & 15);
    qex[((size_t)bh*64 + cand_o)*ND + d_o] = acc[j] + bq[h*64 + d_o];
  }
}

// ---------------------------------------------------------------------------
// 4c) exact M for the 64 candidates: grid (4,64), 16 lanes per candidate
// ---------------------------------------------------------------------------
__global__ __launch_bounds__(256) void k_mexact(const float* __restrict__ qex,
                                                const float* __restrict__ kf,
                                                const int* __restrict__ idxs,
                                                const int* __restrict__ Cand,
                                                float* __restrict__ Mex)
{
  const int bh = blockIdx.y, qtr = blockIdx.x, t = threadIdx.x;
  const int c = qtr*16 + (t >> 4);
  const int dl = t & 15;                    // 4 floats at dl*4
  const int l = Cand[bh*64 + c];
  const float4 q4 = *(const float4*)(&qex[((size_t)bh*64 + c)*ND + dl*4]);
  const float* kbase = kf + (size_t)bh*NS*ND;
  const int* ib = idxs + (size_t)l*NU;
  float mx = -FLT_MAX, sm = 0.f;
  for (int s = 0; s < NU; s++) {
    const int id = ib[s];
    const float4 k4 = *(const float4*)(&kbase[(size_t)id*ND + dl*4]);
    float p = q4.x*k4.x + q4.y*k4.y + q4.z*k4.z + q4.w*k4.w;
    p += __shfl_xor(p, 1, 64);
    p += __shfl_xor(p, 2, 64);
    p += __shfl_xor(p, 4, 64);
    p += __shfl_xor(p, 8, 64);
    mx = fmaxf(mx, p);
    sm += p;
  }
  if (dl == 0) Mex[bh*64 + c] = mx - sm * (1.0f/(float)NS);
}

// ---------------------------------------------------------------------------
// 4d) fused top-45 + Qr gather (one block per bh)
// ---------------------------------------------------------------------------
__global__ __launch_bounds__(256) void k_selq(const float* __restrict__ Mex,
                                              const int* __restrict__ Cand,
                                              const float* __restrict__ qex,
                                              int* __restrict__ Mtop,
                                              ushort_t* __restrict__ Qr)
{
  __shared__ int MslotL[NU];
  const int bh = blockIdx.x, t = threadIdx.x;
  // phase 1: top-45 of 64 (wave 0; value desc, index asc)
  if (t < 64) {
    float val = Mex[bh*64 + t];
    const int n = Cand[bh*64 + t];
    const int slot = t;
    for (int it = 0; it < NU; it++) {
      float wv = val; int wn = n; int ws = slot;
      #pragma unroll
      for (int o = 1; o < 64; o <<= 1) {
        float vo = __shfl_xor(wv, o, 64); int io = __shfl_xor(wn, o, 64); int so = __shfl_xor(ws, o, 64);
        if (vo > wv || (vo == wv && io < wn)) { wv = vo; wn = io; ws = so; }
      }
      if (t == 0) { Mtop[bh*NUP + it] = wn; MslotL[it] = ws; }
      if (n == wn) val = -FLT_MAX;
    }
  }
  __syncthreads();
  // phase 2: Qr gather, pre-scaled by 0.125 (rows 45..47 zero)
  for (int e = t; e < NUP*ND; e += 256) {
    const int u = e >> 6, d = e & 63;
    float v = 0.f;
    if (u < NU) { const int s = MslotL[u]; v = qex[((size_t)bh*64 + s)*ND + d]; }
    Qr[bh*NUP*ND + e] = f2bf(v * 0.125f);
  }
}

// ---------------------------------------------------------------------------
// 6) FLASH: fused scores->softmax->PV with online softmax.
//    Grid 512 = 64 bh x 8 col-segments (blk&63=bh keeps bh on one XCD).
// ---------------------------------------------------------------------------
__global__ __launch_bounds__(256) void k_flash(const ushort_t* __restrict__ Qr,
                                               const ushort_t* __restrict__ kb16,
                                               const ushort_t* __restrict__ vfT,
                                               float* __restrict__ Opart,
                                               float* __restrict__ mpart,
                                               float* __restrict__ lpart)
{
  __shared__ __align__(16) ushort_t Plds[3][16][68];   // f16, wave-private
  const int blk = blockIdx.x;
  const int bh = blk & 63, seg = blk >> 6;
  const int t = threadIdx.x, w = t >> 6, l = t & 63;
  if (w >= 3) return;                                  // no barriers below
  const int row0 = w*16;
  bf16x8 aq[2];
  #pragma unroll
  for (int ks = 0; ks < 2; ks++)
    aq[ks] = *(const bf16x8*)(&Qr[((size_t)bh*NUP + row0 + (l & 15))*ND + ks*32 + (l >> 4)*8]);
  f32x4 o[4] = {};
  float m[4], ls[4];
  #pragma unroll
  for (int j = 0; j < 4; j++) { m[j] = -FLT_MAX; ls[j] = 0.f; }
  const int nbeg = seg*512;
  for (int nc = nbeg; nc < nbeg + 512; nc += 64) {
    f32x4 S[4];
    #pragma unroll
    for (int ct = 0; ct < 4; ct++) {
      f32x4 z = {};
      #pragma unroll
      for (int ks = 0; ks < 2; ks++) {
        bf16x8 bk8 = *(const bf16x8*)(&kb16[((size_t)bh*NS + nc + ct*16 + (l & 15))*ND + ks*32 + (l >> 4)*8]);
        z = __builtin_amdgcn_mfma_f32_16x16x32_bf16(aq[ks], bk8, z, 0, 0, 0);
      }
      S[ct] = z;
    }
    float mx[4];
    #pragma unroll
    for (int j = 0; j < 4; j++)
      mx[j] = fmaxf(fmaxf(S[0][j], S[1][j]), fmaxf(S[2][j], S[3][j]));
    #pragma unroll
    for (int o2 = 1; o2 < 16; o2 <<= 1)
      #pragma unroll
      for (int j = 0; j < 4; j++)
        mx[j] = fmaxf(mx[j], __shfl_xor(mx[j], o2, 64));
    float c[4];
    #pragma unroll
    for (int j = 0; j < 4; j++) {
      const float mn = fmaxf(m[j], mx[j]);
      c[j] = __expf(m[j] - mn);
      m[j] = mn;
      ls[j] *= c[j];
    }
    #pragma unroll
    for (int dt = 0; dt < 4; dt++)
      #pragma unroll
      for (int j = 0; j < 4; j++)
        o[dt][j] *= c[j];
    #pragma unroll
    for (int ct = 0; ct < 4; ct++)
      #pragma unroll
      for (int j = 0; j < 4; j++) {
        const float pv = __expf(S[ct][j] - m[j]);
        ls[j] += pv;
        Plds[w][(l >> 4)*4 + j][ct*16 + (l & 15)] = f2h(pv);
      }
    #pragma unroll
    for (int ks2 = 0; ks2 < 2; ks2++) {
      f16x8 ap = __builtin_bit_cast(f16x8, *(const uint4*)(&Plds[w][l & 15][ks2*32 + (l >> 4)*8]));
      #pragma unroll
      for (int dt = 0; dt < 4; dt++) {
        f16x8 bv8 = __builtin_bit_cast(f16x8, *(const uint4*)(&vfT[((size_t)bh*ND + dt*16 + (l & 15))*NS + nc + ks2*32 + (l >> 4)*8]));
        o[dt] = __builtin_amdgcn_mfma_f32_16x16x32_f16(ap, bv8, o[dt], 0, 0, 0);
      }
    }
  }
  #pragma unroll
  for (int o2 = 1; o2 < 16; o2 <<= 1)
    #pragma unroll
    for (int j = 0; j < 4; j++)
      ls[j] += __shfl_xor(ls[j], o2, 64);
  #pragma unroll
  for (int dt = 0; dt < 4; dt++)
    #pragma unroll
    for (int j = 0; j < 4; j++)
      Opart[(((size_t)bh*8 + seg)*NUP + row0 + (l >> 4)*4 + j)*ND + dt*16 + (l & 15)] = o[dt][j];
  if ((l & 15) == 0) {
    #pragma unroll
    for (int j = 0; j < 4; j++) {
      mpart[((size_t)bh*8 + seg)*NUP + row0 + (l >> 4)*4 + j] = m[j];
      lpart[((size_t)bh*8 + seg)*NUP + row0 + (l >> 4)*4 + j] = ls[j];
    }
  }
}

// ---------------------------------------------------------------------------
// 6b) combine 8 segment partials -> delta; fused uidx init (grid 1024)
// ---------------------------------------------------------------------------
__global__ __launch_bounds__(256) void k_combine(const float* __restrict__ Opart,
                                                 const float* __restrict__ mpart,
                                                 const float* __restrict__ lpart,
                                                 const float* __restrict__ vmean,
                                                 float* __restrict__ delta,
                                                 int* __restrict__ uidx)
{
  const int blk = blockIdx.x, t = threadIdx.x;
  uidx[blk*256 + t] = -1;
  if (blk >= 64) return;
  const int bh = blk;
  for (int e = t; e < NUP*ND; e += 256) {
    const int u = e >> 6, d = e & 63;
    float mg = -FLT_MAX;
    #pragma unroll
    for (int s = 0; s < 8; s++) mg = fmaxf(mg, mpart[((size_t)bh*8 + s)*NUP + u]);
    float On = 0.f, Ln = 0.f;
    #pragma unroll
    for (int s = 0; s < 8; s++) {
      const float wgt = __expf(mpart[((size_t)bh*8 + s)*NUP + u] - mg);
      On += wgt * Opart[(((size_t)bh*8 + s)*NUP + u)*ND + d];
      Ln += wgt * lpart[((size_t)bh*8 + s)*NUP + u];
    }
    delta[((size_t)bh*NUP + u)*ND + d] = On/Ln - vmean[bh*ND + d];
  }
}

// ---------------------------------------------------------------------------
// 8) v mean from vfT (one block per (bh,d), deterministic)
// ---------------------------------------------------------------------------
__global__ __launch_bounds__(256) void k_vmean(const ushort_t* __restrict__ vfT, float* __restrict__ vmean)
{
  __shared__ float red[256];
  const int d = blockIdx.x, bh = blockIdx.y, t = threadIdx.x;
  const ushort_t* vr = vfT + ((size_t)bh*ND + d)*NS;
  float s = 0.f;
  for (int n = t; n < NS; n += 256) s += h2f(vr[n]);
  red[t] = s; __syncthreads();
  for (int st = 128; st > 0; st >>= 1) { if (t < st) red[t] += red[t+st]; __syncthreads(); }
  if (t == 0) vmean[bh*ND + d] = red[0] * (1.0f/(float)NS);
}

// ---------------------------------------------------------------------------
// 10) scatter row-id map (uidx pre-initialized by k_combine)
// ---------------------------------------------------------------------------
__global__ void k_scatter(const int* __restrict__ Mtop, int* __restrict__ uidx)
{
  const int bh = blockIdx.x, t = threadIdx.x;  // 64 threads
  if (t < NU) {
    const int n = Mtop[bh*NUP + t];
    const int b = bh >> 3, h = bh & 7;
    const int nprime = h*512 + (n >> 3);       // reference's reshape-without-transpose
    uidx[((size_t)b*NS + nprime)*8 + (n & 7)] = bh*NUP + t;
  }
}

// ---------------------------------------------------------------------------
// 11) corr (u<45) + base (u==45), grid (46, 64)
// ---------------------------------------------------------------------------
__global__ __launch_bounds__(256) void k_corrbase(const float* __restrict__ delta,
                                                  const float* __restrict__ Wp,
                                                  const int* __restrict__ Mtop,
                                                  const float* __restrict__ vmean,
                                                  const float* __restrict__ Wpsum,
                                                  const float* __restrict__ bp,
                                                  float* __restrict__ corr,
                                                  float* __restrict__ basep)
{
  __shared__ float dl[64];
  const int bh = blockIdx.y, u = blockIdx.x, t = threadIdx.x;
  if (u == 45) {
    if (t < 64) dl[t] = vmean[bh*ND + t];
    __syncthreads();
    for (int c = t; c < 512; c += 256) {
      float s = bp[c];
      #pragma unroll 8
      for (int d2 = 0; d2 < 64; d2++) s += dl[d2] * Wpsum[d2*512 + c];
      basep[bh*512 + c] = s;
    }
    return;
  }
  const int n = Mtop[bh*NUP + u];
  const int j = n & 7;
  if (t < 64) dl[t] = delta[((size_t)bh*NUP + u)*ND + t];
  __syncthreads();
  for (int c = t; c < 512; c += 256) {
    float s = 0.f;
    #pragma unroll 8
    for (int d2 = 0; d2 < 64; d2++) s += dl[d2] * Wp[(size_t)(j*64 + d2)*512 + c];
    corr[((size_t)bh*NUP + u)*512 + c] = s;
  }
}

// ---------------------------------------------------------------------------
// 13) assemble output rows (f32)
// ---------------------------------------------------------------------------
__global__ __launch_bounds__(256) void k_assemble(const float* __restrict__ basep,
                                                  const float* __restrict__ corr,
                                                  const int* __restrict__ uidx,
                                                  float* __restrict__ out)
{
  const int b = blockIdx.y, nprime = blockIdx.x, t = threadIdx.x;
  const int h = nprime >> 9;
  const int* ui = uidx + ((size_t)b*NS + nprime)*8;
  float v0 = basep[(b*8 + h)*512 + t];
  float v1 = basep[(b*8 + h)*512 + 256 + t];
  #pragma unroll
  for (int j = 0; j < 8; j++) {
    const int id = ui[j];
    if (id >= 0) { v0 += corr[(size_t)id*512 + t]; v1 += corr[(size_t)id*512 + 256 + t]; }
  }
  const size_t o = ((size_t)b*NS + nprime)*512;
  out[o + t]       = v0;
  out[o + 256 + t] = v1;
}

// ---------------------------------------------------------------------------
extern "C" void kernel_launch(void* const* d_in, const int* in_sizes, int n_in,
                              void* d_out, int out_size, void* d_ws, size_t ws_size,
                              hipStream_t stream)
{
  (void)in_sizes; (void)n_in; (void)out_size; (void)ws_size;
  const float* x  = (const float*)d_in[0];
  const float* Wq = (const float*)d_in[1];
  const float* bq = (const float*)d_in[2];
  const float* Wk = (const float*)d_in[3];
  const float* bk = (const float*)d_in[4];
  const float* Wv = (const float*)d_in[5];
  const float* bv = (const float*)d_in[6];
  const float* Wp = (const float*)d_in[7];
  const float* bp = (const float*)d_in[8];
  const int* idxs = (const int*)d_in[9];
  float* out      = (float*)d_out;

  // workspace carve-up (peak 205.7 MB; ws >= 205,975,552 established)
  char* w = (char*)d_ws;
  float*    kf    = (float*)(w);                    // 67,108,864  (live until k_mexact done)
  ushort_t* vfT   = (ushort_t*)(w + 67108864);      // 33,554,432  [64][64][4096] f16
  ushort_t* kb16  = (ushort_t*)(w + 100663296);     // 33,554,432  [64][4096][64] bf16
  ushort_t* xh    = (ushort_t*)(w + 134217728);     // 33,554,432  (dead after k_gemm<0> -> tail aliases)
  ushort_t* xl    = (ushort_t*)(w + 167772160);     // 33,554,432  (dead after k_gemm<1>)
  ushort_t* qb16  = (ushort_t*)(w + 167772160);     // ALIAS of xl: written by k_gemm<0>, dead after m_approx
  ushort_t* Qr    = (ushort_t*)(w + 167772160);     // ALIAS of qb16: written by k_selq
  ushort_t* wh    = (ushort_t*)(w + 201326592);     //  1,572,864
  ushort_t* wl    = (ushort_t*)(w + 202899456);     //  1,572,864
  float*    Mv    = (float*)(w + 204472320);        //  1,048,576  (dead after k_topk)
  float*    qex   = (float*)(w + 204472320);        // ALIAS of Mv: [64][64][64] f32
  int*      Mtop  = (int*)(w + 205520896);          //     12,288
  int*      Cand  = (int*)(w + 205533184);          //     16,384
  float*    vmean = (float*)(w + 205549568);        //     16,384
  float*    Wpsum = (float*)(w + 205565952);        //    131,072
  float*    Mex   = (float*)(w + 205697024);        //     16,384  -> end 205,713,408
  // tail aliases over the dead xh region (valid after both k_gemm):
  float*    delta  = (float*)(w + 134217728);       //    786,432
  float*    corr   = (float*)(w + 135004160);       //  6,291,456
  int*      uidx   = (int*)(w + 141295616);         //  1,048,576
  float*    basep  = (float*)(w + 142344192);       //    131,072
  float*    Opart  = (float*)(w + 142475264);       //  6,291,456  [64][8][48][64]
  float*    mpart  = (float*)(w + 148766720);       //     98,304
  float*    lpart  = (float*)(w + 148865024);       //     98,304  -> 148,963,328

  k_prep     <<<16576, 256, 0, stream>>>(Wq, Wk, Wv, Wp, x, wh, wl, Wpsum, xh, xl);
  k_gemm<1>  <<<dim3(8, 256), 256, 0, stream>>>(xh, xl, wh, wl, bq, bk, bv, kf, vfT, kb16, nullptr);
  // xl dead; qb16 (same region) written next. k_gemm<0> reads only xh.
  k_gemm<0>  <<<dim3(4, 256), 256, 0, stream>>>(xh, nullptr, wh, wl, bq, bk, bv, nullptr, nullptr, nullptr, qb16);
  k_m_approx <<<dim3(1024, 64), 256, 0, stream>>>(qb16, kb16, idxs, Mv);
  k_vmean    <<<dim3(64, 64), 256, 0, stream>>>(vfT, vmean);
  k_topk<64,64> <<<64, 256, 0, stream>>>(Mv, Cand);
  // Mv dead; qex (same region) written next. qb16 dead; Qr reuses it.
  k_qexact   <<<dim3(4, 64), 256, 0, stream>>>(x, wh, wl, bq, Cand, qex);
  k_mexact   <<<dim3(4, 64), 256, 0, stream>>>(qex, kf, idxs, Cand, Mex);
  k_selq     <<<64, 256, 0, stream>>>(Mex, Cand, qex, Mtop, Qr);
  // kf dead from here
  k_flash    <<<512, 256, 0, stream>>>(Qr, kb16, vfT, Opart, mpart, lpart);
  k_combine  <<<1024, 256, 0, stream>>>(Opart, mpart, lpart, vmean, delta, uidx);
  k_scatter  <<<64, 64, 0, stream>>>(Mtop, uidx);
  k_corrbase <<<dim3(46, 64), 256, 0, stream>>>(delta, Wp, Mtop, vmean, Wpsum, bp, corr, basep);
  k_assemble <<<dim3(4096, 8), 256, 0, stream>>>(basep, corr, uidx, out);
}